// Round 1
// baseline (463.940 us; speedup 1.0000x reference)
//
#include <hip/hip_runtime.h>
#include <hip/hip_bf16.h>

typedef __bf16 bf16;
typedef __attribute__((ext_vector_type(4))) __bf16 bf16x4;
typedef __attribute__((ext_vector_type(8))) __bf16 bf16x8;
typedef __attribute__((ext_vector_type(4))) float f32x4;

#define B_ 4
#define T_ 2048
#define C_ 1024
#define H_ 16
#define D_ 64
#define BT_ (B_*T_)

#define NEG_INF (-__builtin_inff())

__device__ __forceinline__ void gld16(const void* g, void* l) {
  __builtin_amdgcn_global_load_lds(
      (const __attribute__((address_space(1))) void*)g,
      (__attribute__((address_space(3))) void*)l, 16, 0, 0);
}

// ---------------- preprocessing ----------------

__global__ void cast_x(const float* __restrict__ in, bf16* __restrict__ out) {
  int i = blockIdx.x * 256 + threadIdx.x;
  f32x4 v = reinterpret_cast<const f32x4*>(in)[i];
  bf16x4 o;
  o[0] = (bf16)v[0]; o[1] = (bf16)v[1]; o[2] = (bf16)v[2]; o[3] = (bf16)v[3];
  reinterpret_cast<bf16x4*>(out)[i] = o;
}

// in [R][Cc] fp32  ->  out [Cc][R] bf16
__global__ void transpose_cast(const float* __restrict__ in, bf16* __restrict__ out,
                               int R, int Cc) {
  __shared__ float tile[32][33];
  int tx = threadIdx.x, ty = threadIdx.y;
  int x  = blockIdx.x * 32 + tx;
  int y0 = blockIdx.y * 32;
#pragma unroll
  for (int j = 0; j < 32; j += 8)
    tile[ty + j][tx] = in[(size_t)(y0 + ty + j) * Cc + x];
  __syncthreads();
  int ox  = y0 + tx;
  int oy0 = blockIdx.x * 32;
#pragma unroll
  for (int j = 0; j < 32; j += 8)
    out[(size_t)(oy0 + ty + j) * R + ox] = (bf16)tile[tx][ty + j];
}

// ---------------- GEMM: C[M][N] = A[M][K] @ Bt[N][K]^T + bias ----------------
// EPI=0: scatter to q/k/v bufs (bf16).  EPI=1: plain fp32 out.

template<int EPI>
__global__ __launch_bounds__(256)
void gemm_bt(const bf16* __restrict__ A, const bf16* __restrict__ Bt,
             const float* __restrict__ bias, float* __restrict__ outF,
             bf16* __restrict__ qb, bf16* __restrict__ kb, bf16* __restrict__ vb,
             int M, int N, int K) {
  __shared__ alignas(16) bf16 As[128 * 32];
  __shared__ alignas(16) bf16 Bs[128 * 32];
  const int tid = threadIdx.x;
  const int lane = tid & 63, wid = tid >> 6;
  const int wm = wid >> 1, wn = wid & 1;           // 2x2 waves, 64x64 each
  const int lr = lane & 15, lg = lane >> 4;
  const int m0 = blockIdx.y * 128, n0 = blockIdx.x * 128;

  f32x4 acc[4][4] = {};

  const int ktiles = K >> 5;
  for (int kt = 0; kt < ktiles; ++kt) {
    const int k0 = kt << 5;
#pragma unroll
    for (int j = 0; j < 2; ++j) {
      int s = j * 256 + tid;                       // 512 slots x 16B = 8KB
      int row = s >> 2, ke = (s & 3) << 3;         // 4 slots per 32-elem row
      gld16(A  + (size_t)(m0 + row) * K + k0 + ke, As + s * 8);
      gld16(Bt + (size_t)(n0 + row) * K + k0 + ke, Bs + s * 8);
    }
    __syncthreads();
    bf16x8 af[4], bfr[4];
#pragma unroll
    for (int i = 0; i < 4; i++)
      af[i]  = *(const bf16x8*)(As + ((wm * 64 + i * 16 + lr) << 5) + (lg << 3));
#pragma unroll
    for (int i = 0; i < 4; i++)
      bfr[i] = *(const bf16x8*)(Bs + ((wn * 64 + i * 16 + lr) << 5) + (lg << 3));
#pragma unroll
    for (int i = 0; i < 4; i++)
#pragma unroll
      for (int j = 0; j < 4; j++)
        acc[i][j] = __builtin_amdgcn_mfma_f32_16x16x32_bf16(af[i], bfr[j], acc[i][j], 0, 0, 0);
    __syncthreads();
  }

  if (EPI == 1) {
#pragma unroll
    for (int i = 0; i < 4; i++) {
      int row = m0 + wm * 64 + i * 16 + lg * 4;
#pragma unroll
      for (int j = 0; j < 4; j++) {
        int col = n0 + wn * 64 + j * 16 + lr;
        float bv = bias[col];
#pragma unroll
        for (int r = 0; r < 4; r++)
          outF[(size_t)(row + r) * N + col] = acc[i][j][r] + bv;
      }
    }
  } else {
    const int sect = n0 >> 10;                     // 0=q 1=k 2=v (uniform per block)
#pragma unroll
    for (int i = 0; i < 4; i++) {
      int row = m0 + wm * 64 + i * 16 + lg * 4;
#pragma unroll
      for (int j = 0; j < 4; j++) {
        int col = n0 + wn * 64 + j * 16 + lr;
        float bv = bias[col];
        int cm = col & 1023;
        int h = cm >> 6, d = cm & 63;
#pragma unroll
        for (int r = 0; r < 4; r++) {
          float v = acc[i][j][r] + bv;
          int rt = row + r;
          int b = rt >> 11, t = rt & 2047;
          bf16 o = (bf16)v;
          size_t bh = (size_t)(b * H_ + h);
          if (sect == 0)      qb[(bh * T_ + t) * D_ + d] = o;   // [B,H,T,D]
          else if (sect == 1) kb[(bh * T_ + t) * D_ + d] = o;   // [B,H,T,D]
          else                vb[(bh * D_ + d) * T_ + t] = o;   // [B,H,D,T] (V^T)
        }
      }
    }
  }
}

// ---------------- flash attention ----------------
// grid: (T/64, B*H); 256 threads = 4 waves, wave w owns q rows [q0+16w, q0+16w+16)

__global__ __launch_bounds__(256)
void attn_fwd(const bf16* __restrict__ qb, const bf16* __restrict__ kb,
              const bf16* __restrict__ vb, bf16* __restrict__ yb) {
  __shared__ alignas(16) bf16 Ks[64 * 64];
  __shared__ alignas(16) bf16 Vs[64 * 64];   // holds V^T tile: [d][k_local]
  __shared__ alignas(16) bf16 Ps[4][16][72]; // wave-private P, padded (144B rows)
  const int tid = threadIdx.x;
  const int lane = tid & 63, wid = tid >> 6;
  const int lr = lane & 15, lg = lane >> 4;
  const int bh = blockIdx.y;
  const int q0 = blockIdx.x * 64;

  // Q fragments hoisted to registers (16 rows x D=64 per wave)
  const bf16* qbase = qb + ((size_t)bh * T_ + q0 + wid * 16) * D_;
  bf16x8 aq0 = *(const bf16x8*)(qbase + lr * D_ + lg * 8);
  bf16x8 aq1 = *(const bf16x8*)(qbase + lr * D_ + 32 + lg * 8);

  const char* kbase = (const char*)(kb + (size_t)bh * T_ * D_);
  const char* vbase = (const char*)(vb + (size_t)bh * D_ * T_);

  f32x4 o[4] = {};
  float mrow[4], lrow[4];
#pragma unroll
  for (int r = 0; r < 4; r++) { mrow[r] = NEG_INF; lrow[r] = 0.f; }

  const int ntiles = blockIdx.x + 1;
  for (int t = 0; t < ntiles; ++t) {
    // stage K tile [64][64] and V^T tile [64][64]; XOR-swizzled SOURCE, linear LDS dest
#pragma unroll
    for (int j = 0; j < 2; ++j) {
      int s = j * 256 + tid;
      int row = s >> 3;                      // 8 x 16B slots per 128B row
      int cb = (s & 7) << 4;
      int scb = cb ^ ((row & 7) << 4);       // involution within 8-row stripe
      gld16(kbase + (size_t)(t * 64 + row) * 128 + scb, (char*)Ks + s * 16);
      gld16(vbase + (size_t)row * (T_ * 2) + t * 128 + scb, (char*)Vs + s * 16);
    }
    __syncthreads();

    // S = Q K^T  (k over D=64 -> 2 mfma per 16-col tile)
    f32x4 sv[4];
#pragma unroll
    for (int ni = 0; ni < 4; ni++) {
      int kr = ni * 16 + lr;
      int xr = (kr & 7) << 4;
      bf16x8 b0 = *(const bf16x8*)((const char*)Ks + kr * 128 + ((lg << 4) ^ xr));
      bf16x8 b1 = *(const bf16x8*)((const char*)Ks + kr * 128 + ((64 + (lg << 4)) ^ xr));
      f32x4 z = {0.f, 0.f, 0.f, 0.f};
      z = __builtin_amdgcn_mfma_f32_16x16x32_bf16(aq0, b0, z, 0, 0, 0);
      sv[ni] = __builtin_amdgcn_mfma_f32_16x16x32_bf16(aq1, b1, z, 0, 0, 0);
    }

    // scale + causal mask + online softmax (wave-parallel)
    float p[4][4];
    float tmax[4] = {NEG_INF, NEG_INF, NEG_INF, NEG_INF};
    const bool diag = (t == (int)blockIdx.x);
#pragma unroll
    for (int ni = 0; ni < 4; ni++)
#pragma unroll
      for (int r = 0; r < 4; r++) {
        float v = sv[ni][r] * 0.125f;        // 1/sqrt(64)
        if (diag) {
          int colg = t * 64 + ni * 16 + lr;
          int rowg = q0 + wid * 16 + lg * 4 + r;
          if (colg > rowg) v = NEG_INF;
        }
        p[ni][r] = v;
        tmax[r] = fmaxf(tmax[r], v);
      }
#pragma unroll
    for (int m = 1; m < 16; m <<= 1)
#pragma unroll
      for (int r = 0; r < 4; r++)
        tmax[r] = fmaxf(tmax[r], __shfl_xor(tmax[r], m, 64));
    float alpha[4], rsum[4];
#pragma unroll
    for (int r = 0; r < 4; r++) {
      float mn = fmaxf(mrow[r], tmax[r]);
      alpha[r] = __expf(mrow[r] - mn);       // exp(-inf)=0 on first tile
      mrow[r] = mn;
      rsum[r] = 0.f;
    }
#pragma unroll
    for (int ni = 0; ni < 4; ni++)
#pragma unroll
      for (int r = 0; r < 4; r++) {
        float e = __expf(p[ni][r] - mrow[r]);
        p[ni][r] = e;
        rsum[r] += e;
      }
#pragma unroll
    for (int m = 1; m < 16; m <<= 1)
#pragma unroll
      for (int r = 0; r < 4; r++)
        rsum[r] += __shfl_xor(rsum[r], m, 64);
#pragma unroll
    for (int r = 0; r < 4; r++) lrow[r] = lrow[r] * alpha[r] + rsum[r];
#pragma unroll
    for (int ni = 0; ni < 4; ni++)
#pragma unroll
      for (int r = 0; r < 4; r++)
        o[ni][r] *= alpha[r];

    // P (D-layout) -> wave-private LDS -> A-layout fragments
#pragma unroll
    for (int ni = 0; ni < 4; ni++)
#pragma unroll
      for (int r = 0; r < 4; r++)
        Ps[wid][lg * 4 + r][ni * 16 + lr] = (bf16)p[ni][r];

    // O += P V   (k over kv window 64 -> 2 mfma per 16-col d tile)
#pragma unroll
    for (int ni = 0; ni < 4; ni++) {
      int vr = ni * 16 + lr;
      int xr = (vr & 7) << 4;
#pragma unroll
      for (int ks = 0; ks < 2; ks++) {
        bf16x8 pa = *(const bf16x8*)(&Ps[wid][lr][ks * 32 + lg * 8]);
        bf16x8 bv = *(const bf16x8*)((const char*)Vs + vr * 128 + (((ks << 6) + (lg << 4)) ^ xr));
        o[ni] = __builtin_amdgcn_mfma_f32_16x16x32_bf16(pa, bv, o[ni], 0, 0, 0);
      }
    }
    __syncthreads();
  }

  const int b = bh >> 4, h = bh & 15;
  float inv[4];
#pragma unroll
  for (int r = 0; r < 4; r++) inv[r] = 1.f / lrow[r];
#pragma unroll
  for (int ni = 0; ni < 4; ni++)
#pragma unroll
    for (int r = 0; r < 4; r++) {
      int rowg = q0 + wid * 16 + lg * 4 + r;
      yb[((size_t)(b * T_ + rowg)) * C_ + h * D_ + ni * 16 + lr] = (bf16)(o[ni][r] * inv[r]);
    }
}

// ---------------- launch ----------------

extern "C" void kernel_launch(void* const* d_in, const int* in_sizes, int n_in,
                              void* d_out, int out_size, void* d_ws, size_t ws_size,
                              hipStream_t stream) {
  (void)in_sizes; (void)n_in; (void)out_size; (void)ws_size;
  const float* x      = (const float*)d_in[0];
  const float* w_attn = (const float*)d_in[1];
  const float* b_attn = (const float*)d_in[2];
  const float* w_proj = (const float*)d_in[3];
  const float* b_proj = (const float*)d_in[4];
  float* out = (float*)d_out;

  char* ws = (char*)d_ws;
  bf16* x_bf = (bf16*)ws;  ws += (size_t)BT_ * C_ * 2;      // 16 MB
  bf16* wat  = (bf16*)ws;  ws += (size_t)3 * C_ * C_ * 2;   //  6 MB  [3C][C]
  bf16* wpt  = (bf16*)ws;  ws += (size_t)C_ * C_ * 2;       //  2 MB  [C][C]
  bf16* qbuf = (bf16*)ws;  ws += (size_t)BT_ * C_ * 2;      // 16 MB  [B,H,T,D]
  bf16* kbuf = (bf16*)ws;  ws += (size_t)BT_ * C_ * 2;      // 16 MB  [B,H,T,D]
  bf16* vbuf = (bf16*)ws;  ws += (size_t)BT_ * C_ * 2;      // 16 MB  [B,H,D,T]
  bf16* ybuf = (bf16*)ws;                                    // 16 MB  [B,T,C]

  cast_x<<<(BT_ * C_ / 4) / 256, 256, 0, stream>>>(x, x_bf);
  transpose_cast<<<dim3(3 * C_ / 32, C_ / 32), dim3(32, 8), 0, stream>>>(w_attn, wat, C_, 3 * C_);
  transpose_cast<<<dim3(C_ / 32, C_ / 32), dim3(32, 8), 0, stream>>>(w_proj, wpt, C_, C_);

  gemm_bt<0><<<dim3(3 * C_ / 128, BT_ / 128), 256, 0, stream>>>(
      x_bf, wat, b_attn, nullptr, qbuf, kbuf, vbuf, BT_, 3 * C_, C_);

  attn_fwd<<<dim3(T_ / 64, B_ * H_), 256, 0, stream>>>(qbuf, kbuf, vbuf, ybuf);

  gemm_bt<1><<<dim3(C_ / 128, BT_ / 128), 256, 0, stream>>>(
      ybuf, wpt, b_proj, out, nullptr, nullptr, nullptr, BT_, C_, C_);
}

// Round 2
// 424.910 us; speedup vs baseline: 1.0919x; 1.0919x over previous
//
#include <hip/hip_runtime.h>
#include <hip/hip_bf16.h>

typedef __bf16 bf16;
typedef __attribute__((ext_vector_type(4))) __bf16 bf16x4;
typedef __attribute__((ext_vector_type(8))) __bf16 bf16x8;
typedef __attribute__((ext_vector_type(4))) float f32x4;

#define B_ 4
#define T_ 2048
#define C_ 1024
#define H_ 16
#define D_ 64
#define BT_ (B_*T_)

#define NEG_INF (-__builtin_inff())

__device__ __forceinline__ void gld16(const void* g, void* l) {
  __builtin_amdgcn_global_load_lds(
      (const __attribute__((address_space(1))) void*)g,
      (__attribute__((address_space(3))) void*)l, 16, 0, 0);
}

// ---------------- preprocessing ----------------

__global__ void cast_x(const float* __restrict__ in, bf16* __restrict__ out) {
  int i = blockIdx.x * 256 + threadIdx.x;
  f32x4 v = reinterpret_cast<const f32x4*>(in)[i];
  bf16x4 o;
  o[0] = (bf16)v[0]; o[1] = (bf16)v[1]; o[2] = (bf16)v[2]; o[3] = (bf16)v[3];
  reinterpret_cast<bf16x4*>(out)[i] = o;
}

// in [R][Cc] fp32  ->  out [Cc][R] bf16
__global__ void transpose_cast(const float* __restrict__ in, bf16* __restrict__ out,
                               int R, int Cc) {
  __shared__ float tile[32][33];
  int tx = threadIdx.x, ty = threadIdx.y;
  int x  = blockIdx.x * 32 + tx;
  int y0 = blockIdx.y * 32;
#pragma unroll
  for (int j = 0; j < 32; j += 8)
    tile[ty + j][tx] = in[(size_t)(y0 + ty + j) * Cc + x];
  __syncthreads();
  int ox  = y0 + tx;
  int oy0 = blockIdx.x * 32;
#pragma unroll
  for (int j = 0; j < 32; j += 8)
    out[(size_t)(oy0 + ty + j) * R + ox] = (bf16)tile[tx][ty + j];
}

// ---------------- GEMM: C[M][N] = A[M][K] @ Bt[N][K]^T + bias ----------------

template<int EPI>
__global__ __launch_bounds__(256)
void gemm_bt(const bf16* __restrict__ A, const bf16* __restrict__ Bt,
             const float* __restrict__ bias, float* __restrict__ outF,
             bf16* __restrict__ qb, bf16* __restrict__ kb, bf16* __restrict__ vb,
             int M, int N, int K) {
  __shared__ alignas(16) bf16 As[128 * 32];
  __shared__ alignas(16) bf16 Bs[128 * 32];
  const int tid = threadIdx.x;
  const int lane = tid & 63, wid = tid >> 6;
  const int wm = wid >> 1, wn = wid & 1;           // 2x2 waves, 64x64 each
  const int lr = lane & 15, lg = lane >> 4;
  const int m0 = blockIdx.y * 128, n0 = blockIdx.x * 128;

  f32x4 acc[4][4] = {};

  const int ktiles = K >> 5;
  for (int kt = 0; kt < ktiles; ++kt) {
    const int k0 = kt << 5;
#pragma unroll
    for (int j = 0; j < 2; ++j) {
      int s = j * 256 + tid;                       // 512 slots x 16B = 8KB
      int row = s >> 2, ke = (s & 3) << 3;         // 4 slots per 32-elem row
      gld16(A  + (size_t)(m0 + row) * K + k0 + ke, As + s * 8);
      gld16(Bt + (size_t)(n0 + row) * K + k0 + ke, Bs + s * 8);
    }
    __syncthreads();
    bf16x8 af[4], bfr[4];
#pragma unroll
    for (int i = 0; i < 4; i++)
      af[i]  = *(const bf16x8*)(As + ((wm * 64 + i * 16 + lr) << 5) + (lg << 3));
#pragma unroll
    for (int i = 0; i < 4; i++)
      bfr[i] = *(const bf16x8*)(Bs + ((wn * 64 + i * 16 + lr) << 5) + (lg << 3));
#pragma unroll
    for (int i = 0; i < 4; i++)
#pragma unroll
      for (int j = 0; j < 4; j++)
        acc[i][j] = __builtin_amdgcn_mfma_f32_16x16x32_bf16(af[i], bfr[j], acc[i][j], 0, 0, 0);
    __syncthreads();
  }

  if (EPI == 1) {
#pragma unroll
    for (int i = 0; i < 4; i++) {
      int row = m0 + wm * 64 + i * 16 + lg * 4;
#pragma unroll
      for (int j = 0; j < 4; j++) {
        int col = n0 + wn * 64 + j * 16 + lr;
        float bv = bias[col];
#pragma unroll
        for (int r = 0; r < 4; r++)
          outF[(size_t)(row + r) * N + col] = acc[i][j][r] + bv;
      }
    }
  } else {
    const int sect = n0 >> 10;                     // 0=q 1=k 2=v (uniform per block)
#pragma unroll
    for (int i = 0; i < 4; i++) {
      int row = m0 + wm * 64 + i * 16 + lg * 4;
#pragma unroll
      for (int j = 0; j < 4; j++) {
        int col = n0 + wn * 64 + j * 16 + lr;
        float bv = bias[col];
        int cm = col & 1023;
        int h = cm >> 6, d = cm & 63;
#pragma unroll
        for (int r = 0; r < 4; r++) {
          float v = acc[i][j][r] + bv;
          int rt = row + r;
          int b = rt >> 11, t = rt & 2047;
          bf16 o = (bf16)v;
          size_t bh = (size_t)(b * H_ + h);
          if (sect == 0)      qb[(bh * T_ + t) * D_ + d] = o;   // [B,H,T,D]
          else if (sect == 1) kb[(bh * T_ + t) * D_ + d] = o;   // [B,H,T,D]
          else                vb[(bh * D_ + d) * T_ + t] = o;   // [B,H,D,T] (V^T)
        }
      }
    }
  }
}

// ---------------- flash attention ----------------
// grid: (T/128, B*H); 256 threads = 4 waves, wave w owns 32 q rows.
// Double-buffered K/V staging (counted vmcnt), heavy blocks dispatched first.

__global__ __launch_bounds__(256, 3)
void attn_fwd(const bf16* __restrict__ qg, const bf16* __restrict__ kb,
              const bf16* __restrict__ vb, bf16* __restrict__ yb) {
  __shared__ alignas(16) bf16 Ks[2][64 * 64];
  __shared__ alignas(16) bf16 Vs[2][64 * 64];   // V^T tile: [d][k_local]
  __shared__ alignas(16) bf16 Ps[4][32][72];    // wave-private P, padded
  const int tid = threadIdx.x;
  const int lane = tid & 63, wid = tid >> 6;
  const int lr = lane & 15, lg = lane >> 4;
  const int bh = blockIdx.y;
  const int qblk = gridDim.x - 1 - blockIdx.x;  // heaviest first
  const int q0 = qblk * 128;
  const int wq0 = q0 + wid * 32;

  // Q fragments hoisted to registers (32 rows x D=64 per wave)
  const bf16* qbase = qg + ((size_t)bh * T_ + wq0) * D_;
  bf16x8 aq[2][2];
#pragma unroll
  for (int i = 0; i < 2; i++)
#pragma unroll
    for (int ks = 0; ks < 2; ks++) {
      aq[i][ks] = *(const bf16x8*)(qbase + (i * 16 + lr) * D_ + ks * 32 + lg * 8);
      asm volatile("" : "+v"(aq[i][ks]));    // materialize before staging loop
    }

  const char* kbase = (const char*)(kb + (size_t)bh * T_ * D_);
  const char* vbase = (const char*)(vb + (size_t)bh * D_ * T_);

  f32x4 o[2][4] = {};
  float mrow[2][4], lrow[2][4];
#pragma unroll
  for (int i = 0; i < 2; i++)
#pragma unroll
    for (int r = 0; r < 4; r++) { mrow[i][r] = NEG_INF; lrow[i][r] = 0.f; }

  const int nt = 2 * qblk + 2;

#define STAGE(BF, TT) do {                                                     \
    _Pragma("unroll")                                                          \
    for (int j_ = 0; j_ < 2; ++j_) {                                           \
      int s_ = j_ * 256 + tid;                                                 \
      int row_ = s_ >> 3;                                                      \
      int cb_ = (s_ & 7) << 4;                                                 \
      int scb_ = cb_ ^ ((row_ & 7) << 4);                                      \
      gld16(kbase + (size_t)((TT) * 64 + row_) * 128 + scb_,                   \
            (char*)Ks[BF] + s_ * 16);                                          \
      gld16(vbase + (size_t)row_ * (T_ * 2) + (TT) * 128 + scb_,               \
            (char*)Vs[BF] + s_ * 16);                                          \
    }                                                                          \
  } while (0)

  STAGE(0, 0);
  int cur = 0;
  for (int t = 0; t < nt; ++t) {
    if (t + 1 < nt) {
      STAGE(cur ^ 1, t + 1);
      asm volatile("s_waitcnt vmcnt(4)" ::: "memory");   // cur's 4 loads done
    } else {
      asm volatile("s_waitcnt vmcnt(0)" ::: "memory");
    }
    __builtin_amdgcn_s_barrier();
    asm volatile("" ::: "memory");

    const char* Kc = (const char*)Ks[cur];
    const char* Vc = (const char*)Vs[cur];

    // S = Q K^T  -> sv[i][ni], i = 16-row group, ni = 16-col group
    f32x4 sv[2][4];
#pragma unroll
    for (int ni = 0; ni < 4; ni++) {
      int kr = ni * 16 + lr;
      int xr = (kr & 7) << 4;
      bf16x8 b0 = *(const bf16x8*)(Kc + kr * 128 + ((lg << 4) ^ xr));
      bf16x8 b1 = *(const bf16x8*)(Kc + kr * 128 + ((64 + (lg << 4)) ^ xr));
      f32x4 z0 = {0.f, 0.f, 0.f, 0.f};
      f32x4 z1 = {0.f, 0.f, 0.f, 0.f};
      z0 = __builtin_amdgcn_mfma_f32_16x16x32_bf16(aq[0][0], b0, z0, 0, 0, 0);
      sv[0][ni] = __builtin_amdgcn_mfma_f32_16x16x32_bf16(aq[0][1], b1, z0, 0, 0, 0);
      z1 = __builtin_amdgcn_mfma_f32_16x16x32_bf16(aq[1][0], b0, z1, 0, 0, 0);
      sv[1][ni] = __builtin_amdgcn_mfma_f32_16x16x32_bf16(aq[1][1], b1, z1, 0, 0, 0);
    }

    // scale + causal mask + online softmax (wave-parallel, in place in sv)
    const bool needmask = (t >= nt - 2);
    float tmax[2][4];
#pragma unroll
    for (int i = 0; i < 2; i++)
#pragma unroll
      for (int r = 0; r < 4; r++) tmax[i][r] = NEG_INF;
#pragma unroll
    for (int i = 0; i < 2; i++)
#pragma unroll
      for (int ni = 0; ni < 4; ni++)
#pragma unroll
        for (int r = 0; r < 4; r++) {
          float v = sv[i][ni][r] * 0.125f;     // 1/sqrt(64)
          if (needmask) {
            int colg = t * 64 + ni * 16 + lr;
            int rowg = wq0 + i * 16 + lg * 4 + r;
            if (colg > rowg) v = NEG_INF;
          }
          sv[i][ni][r] = v;
          tmax[i][r] = fmaxf(tmax[i][r], v);
        }
#pragma unroll
    for (int m = 1; m < 16; m <<= 1)
#pragma unroll
      for (int i = 0; i < 2; i++)
#pragma unroll
        for (int r = 0; r < 4; r++)
          tmax[i][r] = fmaxf(tmax[i][r], __shfl_xor(tmax[i][r], m, 64));
    float rsum[2][4];
#pragma unroll
    for (int i = 0; i < 2; i++)
#pragma unroll
      for (int r = 0; r < 4; r++) {
        float mn = fmaxf(mrow[i][r], tmax[i][r]);
        float alpha = __expf(mrow[i][r] - mn);   // exp(-inf)=0 first tile
        mrow[i][r] = mn;
        lrow[i][r] *= alpha;
#pragma unroll
        for (int ni = 0; ni < 4; ni++) o[i][ni][r] *= alpha;
        rsum[i][r] = 0.f;
      }
#pragma unroll
    for (int i = 0; i < 2; i++)
#pragma unroll
      for (int ni = 0; ni < 4; ni++)
#pragma unroll
        for (int r = 0; r < 4; r++) {
          float e = __expf(sv[i][ni][r] - mrow[i][r]);
          sv[i][ni][r] = e;
          rsum[i][r] += e;
        }
#pragma unroll
    for (int m = 1; m < 16; m <<= 1)
#pragma unroll
      for (int i = 0; i < 2; i++)
#pragma unroll
        for (int r = 0; r < 4; r++)
          rsum[i][r] += __shfl_xor(rsum[i][r], m, 64);
#pragma unroll
    for (int i = 0; i < 2; i++)
#pragma unroll
      for (int r = 0; r < 4; r++) lrow[i][r] += rsum[i][r];

    // P (D-layout) -> wave-private LDS (A-layout source)
#pragma unroll
    for (int i = 0; i < 2; i++)
#pragma unroll
      for (int ni = 0; ni < 4; ni++)
#pragma unroll
        for (int r = 0; r < 4; r++)
          Ps[wid][i * 16 + lg * 4 + r][ni * 16 + lr] = (bf16)sv[i][ni][r];

    // O += P V
#pragma unroll
    for (int ks = 0; ks < 2; ks++) {
      bf16x8 pa0 = *(const bf16x8*)(&Ps[wid][lr][ks * 32 + lg * 8]);
      bf16x8 pa1 = *(const bf16x8*)(&Ps[wid][16 + lr][ks * 32 + lg * 8]);
#pragma unroll
      for (int ni = 0; ni < 4; ni++) {
        int vr = ni * 16 + lr;
        int xr = (vr & 7) << 4;
        bf16x8 bv = *(const bf16x8*)(Vc + vr * 128 + (((ks << 6) + (lg << 4)) ^ xr));
        o[0][ni] = __builtin_amdgcn_mfma_f32_16x16x32_bf16(pa0, bv, o[0][ni], 0, 0, 0);
        o[1][ni] = __builtin_amdgcn_mfma_f32_16x16x32_bf16(pa1, bv, o[1][ni], 0, 0, 0);
      }
    }

    asm volatile("s_waitcnt lgkmcnt(0)" ::: "memory");
    __builtin_amdgcn_s_barrier();
    cur ^= 1;
  }
#undef STAGE

  const int b = bh >> 4, h = bh & 15;
#pragma unroll
  for (int i = 0; i < 2; i++) {
    float inv[4];
#pragma unroll
    for (int r = 0; r < 4; r++) inv[r] = 1.f / lrow[i][r];
#pragma unroll
    for (int ni = 0; ni < 4; ni++)
#pragma unroll
      for (int r = 0; r < 4; r++) {
        int rowg = wq0 + i * 16 + lg * 4 + r;
        yb[((size_t)(b * T_ + rowg)) * C_ + h * D_ + ni * 16 + lr] =
            (bf16)(o[i][ni][r] * inv[r]);
      }
  }
}

// ---------------- launch ----------------

extern "C" void kernel_launch(void* const* d_in, const int* in_sizes, int n_in,
                              void* d_out, int out_size, void* d_ws, size_t ws_size,
                              hipStream_t stream) {
  (void)in_sizes; (void)n_in; (void)out_size; (void)ws_size;
  const float* x      = (const float*)d_in[0];
  const float* w_attn = (const float*)d_in[1];
  const float* b_attn = (const float*)d_in[2];
  const float* w_proj = (const float*)d_in[3];
  const float* b_proj = (const float*)d_in[4];
  float* out = (float*)d_out;

  char* ws = (char*)d_ws;
  bf16* x_bf = (bf16*)ws;  ws += (size_t)BT_ * C_ * 2;      // 16 MB
  bf16* wat  = (bf16*)ws;  ws += (size_t)3 * C_ * C_ * 2;   //  6 MB  [3C][C]
  bf16* wpt  = (bf16*)ws;  ws += (size_t)C_ * C_ * 2;       //  2 MB  [C][C]
  bf16* qbuf = (bf16*)ws;  ws += (size_t)BT_ * C_ * 2;      // 16 MB  [B,H,T,D]
  bf16* kbuf = (bf16*)ws;  ws += (size_t)BT_ * C_ * 2;      // 16 MB  [B,H,T,D]
  bf16* vbuf = (bf16*)ws;  ws += (size_t)BT_ * C_ * 2;      // 16 MB  [B,H,D,T]
  bf16* ybuf = (bf16*)ws;                                    // 16 MB  [B,T,C]

  cast_x<<<(BT_ * C_ / 4) / 256, 256, 0, stream>>>(x, x_bf);
  transpose_cast<<<dim3(3 * C_ / 32, C_ / 32), dim3(32, 8), 0, stream>>>(w_attn, wat, C_, 3 * C_);
  transpose_cast<<<dim3(C_ / 32, C_ / 32), dim3(32, 8), 0, stream>>>(w_proj, wpt, C_, C_);

  gemm_bt<0><<<dim3(3 * C_ / 128, BT_ / 128), 256, 0, stream>>>(
      x_bf, wat, b_attn, nullptr, qbuf, kbuf, vbuf, BT_, 3 * C_, C_);

  attn_fwd<<<dim3(T_ / 128, B_ * H_), 256, 0, stream>>>(qbuf, kbuf, vbuf, ybuf);

  gemm_bt<1><<<dim3(C_ / 128, BT_ / 128), 256, 0, stream>>>(
      ybuf, wpt, b_proj, out, nullptr, nullptr, nullptr, BT_, C_, C_);
}

// Round 3
// 321.575 us; speedup vs baseline: 1.4427x; 1.3213x over previous
//
#include <hip/hip_runtime.h>
#include <hip/hip_bf16.h>

typedef __bf16 bf16;
typedef __attribute__((ext_vector_type(4))) __bf16 bf16x4;
typedef __attribute__((ext_vector_type(8))) __bf16 bf16x8;
typedef __attribute__((ext_vector_type(4))) float f32x4;
typedef __attribute__((ext_vector_type(16))) float f32x16;
typedef __attribute__((ext_vector_type(2))) unsigned u32x2;
typedef __attribute__((ext_vector_type(4))) unsigned u32x4;

#define B_ 4
#define T_ 2048
#define C_ 1024
#define H_ 16
#define D_ 64
#define BT_ (B_*T_)

#define NEG_INF (-__builtin_inff())

__device__ __forceinline__ void gld16(const void* g, void* l) {
  __builtin_amdgcn_global_load_lds(
      (const __attribute__((address_space(1))) void*)g,
      (__attribute__((address_space(3))) void*)l, 16, 0, 0);
}

__device__ __forceinline__ unsigned cvtpk(float lo, float hi) {
  unsigned r;
  asm("v_cvt_pk_bf16_f32 %0, %1, %2" : "=v"(r) : "v"(lo), "v"(hi));
  return r;
}

// ---------------- preprocessing ----------------

__global__ void cast_x(const float* __restrict__ in, bf16* __restrict__ out) {
  int i = blockIdx.x * 256 + threadIdx.x;
  f32x4 v = reinterpret_cast<const f32x4*>(in)[i];
  bf16x4 o;
  o[0] = (bf16)v[0]; o[1] = (bf16)v[1]; o[2] = (bf16)v[2]; o[3] = (bf16)v[3];
  reinterpret_cast<bf16x4*>(out)[i] = o;
}

// in [R][Cc] fp32  ->  out [Cc][R] bf16
__global__ void transpose_cast(const float* __restrict__ in, bf16* __restrict__ out,
                               int R, int Cc) {
  __shared__ float tile[32][33];
  int tx = threadIdx.x, ty = threadIdx.y;
  int x  = blockIdx.x * 32 + tx;
  int y0 = blockIdx.y * 32;
#pragma unroll
  for (int j = 0; j < 32; j += 8)
    tile[ty + j][tx] = in[(size_t)(y0 + ty + j) * Cc + x];
  __syncthreads();
  int ox  = y0 + tx;
  int oy0 = blockIdx.x * 32;
#pragma unroll
  for (int j = 0; j < 32; j += 8)
    out[(size_t)(oy0 + ty + j) * R + ox] = (bf16)tile[tx][ty + j];
}

// ---------------- GEMM: C[M][N] = A[M][K] @ Bt[N][K]^T + bias ----------------

template<int EPI>
__global__ __launch_bounds__(256)
void gemm_bt(const bf16* __restrict__ A, const bf16* __restrict__ Bt,
             const float* __restrict__ bias, float* __restrict__ outF,
             bf16* __restrict__ qb, bf16* __restrict__ kb, bf16* __restrict__ vb,
             int M, int N, int K) {
  __shared__ alignas(16) bf16 As[128 * 32];
  __shared__ alignas(16) bf16 Bs[128 * 32];
  const int tid = threadIdx.x;
  const int lane = tid & 63, wid = tid >> 6;
  const int wm = wid >> 1, wn = wid & 1;           // 2x2 waves, 64x64 each
  const int lr = lane & 15, lg = lane >> 4;
  const int m0 = blockIdx.y * 128, n0 = blockIdx.x * 128;

  f32x4 acc[4][4] = {};

  const int ktiles = K >> 5;
  for (int kt = 0; kt < ktiles; ++kt) {
    const int k0 = kt << 5;
#pragma unroll
    for (int j = 0; j < 2; ++j) {
      int s = j * 256 + tid;                       // 512 slots x 16B = 8KB
      int row = s >> 2, ke = (s & 3) << 3;         // 4 slots per 32-elem row
      gld16(A  + (size_t)(m0 + row) * K + k0 + ke, As + s * 8);
      gld16(Bt + (size_t)(n0 + row) * K + k0 + ke, Bs + s * 8);
    }
    __syncthreads();
    bf16x8 af[4], bfr[4];
#pragma unroll
    for (int i = 0; i < 4; i++)
      af[i]  = *(const bf16x8*)(As + ((wm * 64 + i * 16 + lr) << 5) + (lg << 3));
#pragma unroll
    for (int i = 0; i < 4; i++)
      bfr[i] = *(const bf16x8*)(Bs + ((wn * 64 + i * 16 + lr) << 5) + (lg << 3));
#pragma unroll
    for (int i = 0; i < 4; i++)
#pragma unroll
      for (int j = 0; j < 4; j++)
        acc[i][j] = __builtin_amdgcn_mfma_f32_16x16x32_bf16(af[i], bfr[j], acc[i][j], 0, 0, 0);
    __syncthreads();
  }

  if (EPI == 1) {
#pragma unroll
    for (int i = 0; i < 4; i++) {
      int row = m0 + wm * 64 + i * 16 + lg * 4;
#pragma unroll
      for (int j = 0; j < 4; j++) {
        int col = n0 + wn * 64 + j * 16 + lr;
        float bv = bias[col];
#pragma unroll
        for (int r = 0; r < 4; r++)
          outF[(size_t)(row + r) * N + col] = acc[i][j][r] + bv;
      }
    }
  } else {
    const int sect = n0 >> 10;                     // 0=q 1=k 2=v (uniform per block)
#pragma unroll
    for (int i = 0; i < 4; i++) {
      int row = m0 + wm * 64 + i * 16 + lg * 4;
#pragma unroll
      for (int j = 0; j < 4; j++) {
        int col = n0 + wn * 64 + j * 16 + lr;
        float bv = bias[col];
        int cm = col & 1023;
        int h = cm >> 6, d = cm & 63;
#pragma unroll
        for (int r = 0; r < 4; r++) {
          float v = acc[i][j][r] + bv;
          int rt = row + r;
          int b = rt >> 11, t = rt & 2047;
          bf16 o = (bf16)v;
          size_t bh = (size_t)(b * H_ + h);
          if (sect == 0)      qb[(bh * T_ + t) * D_ + d] = o;   // [B,H,T,D]
          else if (sect == 1) kb[(bh * T_ + t) * D_ + d] = o;   // [B,H,T,D]
          else                vb[(bh * D_ + d) * T_ + t] = o;   // [B,H,D,T] (V^T)
        }
      }
    }
  }
}

// ---------------- flash attention (32x32 swapped-operand, in-register softmax) ----
// grid: (T/128, B*H); 256 threads = 4 waves, wave w owns 32 q rows.
// S^T = mfma(K, Q): lane owns q-col = lane&31, k-row = (r&3)+8*(r>>2)+4*hi.
// O^T = mfma(V^T, P^T): rescale is lane-uniform; P^T built in-register via
// cvt_pk_bf16 + permlane32_swap. LDS = 32KB -> 4 blocks/CU (full grid resident).

#if __has_builtin(__builtin_amdgcn_permlane32_swap)
#define PERMSWAP(A, B, LOW, HIW) do {                                           \
    auto _r = __builtin_amdgcn_permlane32_swap((unsigned)(A), (unsigned)(B),    \
                                               false, false);                   \
    __builtin_memcpy(&(LOW), &_r, 4);                                           \
    __builtin_memcpy(&(HIW), (const char*)&_r + 4, 4);                          \
  } while (0)
#else
#define PERMSWAP(A, B, LOW, HIW) do {                                           \
    unsigned _sb = (unsigned)__shfl_xor((int)(B), 32, 64);                      \
    unsigned _sa = (unsigned)__shfl_xor((int)(A), 32, 64);                      \
    (LOW) = hi ? _sb : (A);                                                     \
    (HIW) = hi ? (B) : _sa;                                                     \
  } while (0)
#endif

__global__ __launch_bounds__(256, 4)
void attn_fwd(const bf16* __restrict__ qg, const bf16* __restrict__ kg,
              const bf16* __restrict__ vg, bf16* __restrict__ yb) {
  __shared__ alignas(16) bf16 Ks[2][64 * 64];
  __shared__ alignas(16) bf16 Vs[2][64 * 64];   // V^T tile: [d][k_local]
  const int tid = threadIdx.x;
  const int lane = tid & 63, wid = tid >> 6;
  const int hi = lane >> 5, lq = lane & 31;
  const int xr = (lq & 7) << 4;
  const int bh = blockIdx.y;
  const int qblk = gridDim.x - 1 - blockIdx.x;  // heaviest first
  const int wq0 = qblk * 128 + wid * 32;
  const int qrow = wq0 + lq;

  const char* kbase = (const char*)(kg + (size_t)bh * T_ * D_);
  const char* vbase = (const char*)(vg + (size_t)bh * D_ * T_);

#define STAGE(BF, TT) do {                                                     \
    _Pragma("unroll")                                                          \
    for (int j_ = 0; j_ < 2; ++j_) {                                           \
      int s_ = j_ * 256 + tid;                                                 \
      int row_ = s_ >> 3;                                                      \
      int scb_ = ((s_ & 7) << 4) ^ ((row_ & 7) << 4);                          \
      gld16(kbase + (size_t)((TT) * 64 + row_) * 128 + scb_,                   \
            (char*)Ks[BF] + s_ * 16);                                          \
      gld16(vbase + (size_t)row_ * (T_ * 2) + (TT) * 128 + scb_,               \
            (char*)Vs[BF] + s_ * 16);                                          \
    }                                                                          \
  } while (0)

  STAGE(0, 0);

  // Q B-fragments: lane holds q-col = qrow, d = 16s + 8hi + e
  const bf16* qptr = qg + ((size_t)bh * T_ + qrow) * D_ + hi * 8;
  bf16x8 qf[4];
#pragma unroll
  for (int s = 0; s < 4; s++) {
    qf[s] = *(const bf16x8*)(qptr + 16 * s);
    asm volatile("" : "+v"(qf[s]));
  }

  f32x16 o[2] = {};              // O^T: block db rows d=32db+crow, col q=lq
  float mrow = NEG_INF, lrow = 0.f;
  const int nt = 2 * qblk + 2;
  int cur = 0;

  for (int t = 0; t < nt; ++t) {
    asm volatile("s_waitcnt vmcnt(0)" ::: "memory");
    __builtin_amdgcn_s_barrier();
    asm volatile("" ::: "memory");
    if (t + 1 < nt) STAGE(cur ^ 1, t + 1);

    const char* Kc = (const char*)Ks[cur];
    const char* Vc = (const char*)Vs[cur];

    // S^T[k][q] for this wave's 32 q cols; 2 blocks of 32 k
    f32x16 S[2] = {};
    __builtin_amdgcn_s_setprio(1);
#pragma unroll
    for (int s = 0; s < 4; s++) {
#pragma unroll
      for (int b = 0; b < 2; b++) {
        bf16x8 kf = *(const bf16x8*)(Kc + (b * 32 + lq) * 128 +
                                     ((32 * s + 16 * hi) ^ xr));
        S[b] = __builtin_amdgcn_mfma_f32_32x32x16_bf16(kf, qf[s], S[b], 0, 0, 0);
      }
    }
    __builtin_amdgcn_s_setprio(0);

    // causal mask (raw-score domain)
    if (t >= nt - 2) {
#pragma unroll
      for (int b = 0; b < 2; b++)
#pragma unroll
        for (int r = 0; r < 16; r++) {
          int kgl = t * 64 + b * 32 + (r & 3) + 8 * (r >> 2) + 4 * hi;
          if (kgl > qrow) S[b][r] = NEG_INF;
        }
    }

    // online softmax, fully in-register (one cross-lane op per reduce)
    float tm = NEG_INF;
#pragma unroll
    for (int b = 0; b < 2; b++)
#pragma unroll
      for (int r = 0; r < 16; r++) tm = fmaxf(tm, S[b][r]);
    tm = fmaxf(tm, __shfl_xor(tm, 32, 64));

    float mn = fmaxf(mrow, 0.125f * tm);
    float alpha = __expf(mrow - mn);     // exp(-inf)=0 on first tile
    mrow = mn;
    float rs = 0.f;
#pragma unroll
    for (int b = 0; b < 2; b++)
#pragma unroll
      for (int r = 0; r < 16; r++) {
        float e = __expf(fmaf(S[b][r], 0.125f, -mn));
        S[b][r] = e;
        rs += e;
      }
    rs += __shfl_xor(rs, 32, 64);
    lrow = lrow * alpha + rs;
#pragma unroll
    for (int db = 0; db < 2; db++)
#pragma unroll
      for (int r = 0; r < 16; r++) o[db][r] *= alpha;

    // O^T += V^T * P^T ; P^T B-fragment built via cvt_pk + permlane32_swap
    __builtin_amdgcn_s_setprio(1);
#pragma unroll
    for (int ks = 0; ks < 4; ks++) {
      const int b = ks >> 1, hf = ks & 1;
      unsigned A0 = cvtpk(S[b][8 * hf + 0], S[b][8 * hf + 1]);
      unsigned A1 = cvtpk(S[b][8 * hf + 2], S[b][8 * hf + 3]);
      unsigned B0 = cvtpk(S[b][8 * hf + 4], S[b][8 * hf + 5]);
      unsigned B1 = cvtpk(S[b][8 * hf + 6], S[b][8 * hf + 7]);
      unsigned w0, w1, w2, w3;
      PERMSWAP(A0, B0, w0, w2);
      PERMSWAP(A1, B1, w1, w3);
      u32x4 wv = {w0, w1, w2, w3};
      bf16x8 pf = __builtin_bit_cast(bf16x8, wv);
#pragma unroll
      for (int db = 0; db < 2; db++) {
        bf16x8 vf = *(const bf16x8*)(Vc + (db * 32 + lq) * 128 +
                                     ((32 * ks + 16 * hi) ^ xr));
        o[db] = __builtin_amdgcn_mfma_f32_32x32x16_bf16(vf, pf, o[db], 0, 0, 0);
      }
    }
    __builtin_amdgcn_s_setprio(0);
    cur ^= 1;
  }
#undef STAGE

  // epilogue: O^T lane holds q=qrow col; d = 32db + 8rq + 4hi + rr
  float inv = 1.f / lrow;
  const int b_ = bh >> 4, h = bh & 15;
  bf16* yrow = yb + ((size_t)(b_ * T_ + qrow)) * C_ + h * 64 + hi * 4;
#pragma unroll
  for (int db = 0; db < 2; db++)
#pragma unroll
    for (int rq = 0; rq < 4; rq++) {
      unsigned w0 = cvtpk(o[db][4 * rq + 0] * inv, o[db][4 * rq + 1] * inv);
      unsigned w1 = cvtpk(o[db][4 * rq + 2] * inv, o[db][4 * rq + 3] * inv);
      u32x2 wv = {w0, w1};
      *(u32x2*)(yrow + db * 32 + rq * 8) = wv;
    }
}

// ---------------- launch ----------------

extern "C" void kernel_launch(void* const* d_in, const int* in_sizes, int n_in,
                              void* d_out, int out_size, void* d_ws, size_t ws_size,
                              hipStream_t stream) {
  (void)in_sizes; (void)n_in; (void)out_size; (void)ws_size;
  const float* x      = (const float*)d_in[0];
  const float* w_attn = (const float*)d_in[1];
  const float* b_attn = (const float*)d_in[2];
  const float* w_proj = (const float*)d_in[3];
  const float* b_proj = (const float*)d_in[4];
  float* out = (float*)d_out;

  char* ws = (char*)d_ws;
  bf16* x_bf = (bf16*)ws;  ws += (size_t)BT_ * C_ * 2;      // 16 MB
  bf16* wat  = (bf16*)ws;  ws += (size_t)3 * C_ * C_ * 2;   //  6 MB  [3C][C]
  bf16* wpt  = (bf16*)ws;  ws += (size_t)C_ * C_ * 2;       //  2 MB  [C][C]
  bf16* qbuf = (bf16*)ws;  ws += (size_t)BT_ * C_ * 2;      // 16 MB  [B,H,T,D]
  bf16* kbuf = (bf16*)ws;  ws += (size_t)BT_ * C_ * 2;      // 16 MB  [B,H,T,D]
  bf16* vbuf = (bf16*)ws;  ws += (size_t)BT_ * C_ * 2;      // 16 MB  [B,H,D,T]
  bf16* ybuf = (bf16*)ws;                                    // 16 MB  [B,T,C]

  cast_x<<<(BT_ * C_ / 4) / 256, 256, 0, stream>>>(x, x_bf);
  transpose_cast<<<dim3(3 * C_ / 32, C_ / 32), dim3(32, 8), 0, stream>>>(w_attn, wat, C_, 3 * C_);
  transpose_cast<<<dim3(C_ / 32, C_ / 32), dim3(32, 8), 0, stream>>>(w_proj, wpt, C_, C_);

  gemm_bt<0><<<dim3(3 * C_ / 128, BT_ / 128), 256, 0, stream>>>(
      x_bf, wat, b_attn, nullptr, qbuf, kbuf, vbuf, BT_, 3 * C_, C_);

  attn_fwd<<<dim3(T_ / 128, B_ * H_), 256, 0, stream>>>(qbuf, kbuf, vbuf, ybuf);

  gemm_bt<1><<<dim3(C_ / 128, BT_ / 128), 256, 0, stream>>>(
      ybuf, wpt, b_proj, out, nullptr, nullptr, nullptr, BT_, C_, C_);
}

// Round 4
// 299.530 us; speedup vs baseline: 1.5489x; 1.0736x over previous
//
#include <hip/hip_runtime.h>
#include <hip/hip_bf16.h>

typedef __bf16 bf16;
typedef __attribute__((ext_vector_type(4))) __bf16 bf16x4;
typedef __attribute__((ext_vector_type(8))) __bf16 bf16x8;
typedef __attribute__((ext_vector_type(4))) float f32x4;
typedef __attribute__((ext_vector_type(16))) float f32x16;
typedef __attribute__((ext_vector_type(2))) unsigned u32x2;
typedef __attribute__((ext_vector_type(4))) unsigned u32x4;

#define B_ 4
#define T_ 2048
#define C_ 1024
#define H_ 16
#define D_ 64
#define BT_ (B_*T_)

#define NEG_INF (-__builtin_inff())

__device__ __forceinline__ void gld16(const void* g, void* l) {
  __builtin_amdgcn_global_load_lds(
      (const __attribute__((address_space(1))) void*)g,
      (__attribute__((address_space(3))) void*)l, 16, 0, 0);
}

__device__ __forceinline__ unsigned cvtpk(float lo, float hi) {
  unsigned r;
  asm("v_cvt_pk_bf16_f32 %0, %1, %2" : "=v"(r) : "v"(lo), "v"(hi));
  return r;
}

// ---------------- preprocessing ----------------

__global__ void cast_x(const float* __restrict__ in, bf16* __restrict__ out) {
  int i = blockIdx.x * 256 + threadIdx.x;
  f32x4 v = reinterpret_cast<const f32x4*>(in)[i];
  bf16x4 o;
  o[0] = (bf16)v[0]; o[1] = (bf16)v[1]; o[2] = (bf16)v[2]; o[3] = (bf16)v[3];
  reinterpret_cast<bf16x4*>(out)[i] = o;
}

// in [R][Cc] fp32  ->  out [Cc][R] bf16
__global__ void transpose_cast(const float* __restrict__ in, bf16* __restrict__ out,
                               int R, int Cc) {
  __shared__ float tile[32][33];
  int tx = threadIdx.x, ty = threadIdx.y;
  int x  = blockIdx.x * 32 + tx;
  int y0 = blockIdx.y * 32;
#pragma unroll
  for (int j = 0; j < 32; j += 8)
    tile[ty + j][tx] = in[(size_t)(y0 + ty + j) * Cc + x];
  __syncthreads();
  int ox  = y0 + tx;
  int oy0 = blockIdx.x * 32;
#pragma unroll
  for (int j = 0; j < 32; j += 8)
    out[(size_t)(oy0 + ty + j) * R + ox] = (bf16)tile[tx][ty + j];
}

// ---------------- GEMM: C[M][N] = A[M][K] @ Bt[N][K]^T + bias ----------------

template<int EPI>
__global__ __launch_bounds__(256)
void gemm_bt(const bf16* __restrict__ A, const bf16* __restrict__ Bt,
             const float* __restrict__ bias, float* __restrict__ outF,
             bf16* __restrict__ qb, bf16* __restrict__ kb, bf16* __restrict__ vb,
             int M, int N, int K) {
  __shared__ alignas(16) bf16 As[128 * 32];
  __shared__ alignas(16) bf16 Bs[128 * 32];
  const int tid = threadIdx.x;
  const int lane = tid & 63, wid = tid >> 6;
  const int wm = wid >> 1, wn = wid & 1;           // 2x2 waves, 64x64 each
  const int lr = lane & 15, lg = lane >> 4;
  const int m0 = blockIdx.y * 128, n0 = blockIdx.x * 128;

  f32x4 acc[4][4] = {};

  const int ktiles = K >> 5;
  for (int kt = 0; kt < ktiles; ++kt) {
    const int k0 = kt << 5;
#pragma unroll
    for (int j = 0; j < 2; ++j) {
      int s = j * 256 + tid;                       // 512 slots x 16B = 8KB
      int row = s >> 2, ke = (s & 3) << 3;         // 4 slots per 32-elem row
      gld16(A  + (size_t)(m0 + row) * K + k0 + ke, As + s * 8);
      gld16(Bt + (size_t)(n0 + row) * K + k0 + ke, Bs + s * 8);
    }
    __syncthreads();
    bf16x8 af[4], bfr[4];
#pragma unroll
    for (int i = 0; i < 4; i++)
      af[i]  = *(const bf16x8*)(As + ((wm * 64 + i * 16 + lr) << 5) + (lg << 3));
#pragma unroll
    for (int i = 0; i < 4; i++)
      bfr[i] = *(const bf16x8*)(Bs + ((wn * 64 + i * 16 + lr) << 5) + (lg << 3));
#pragma unroll
    for (int i = 0; i < 4; i++)
#pragma unroll
      for (int j = 0; j < 4; j++)
        acc[i][j] = __builtin_amdgcn_mfma_f32_16x16x32_bf16(af[i], bfr[j], acc[i][j], 0, 0, 0);
    __syncthreads();
  }

  if (EPI == 1) {
#pragma unroll
    for (int i = 0; i < 4; i++) {
      int row = m0 + wm * 64 + i * 16 + lg * 4;
#pragma unroll
      for (int j = 0; j < 4; j++) {
        int col = n0 + wn * 64 + j * 16 + lr;
        float bv = bias[col];
#pragma unroll
        for (int r = 0; r < 4; r++)
          outF[(size_t)(row + r) * N + col] = acc[i][j][r] + bv;
      }
    }
  } else {
    const int sect = n0 >> 10;                     // 0=q 1=k 2=v (uniform per block)
#pragma unroll
    for (int i = 0; i < 4; i++) {
      int row = m0 + wm * 64 + i * 16 + lg * 4;
#pragma unroll
      for (int j = 0; j < 4; j++) {
        int col = n0 + wn * 64 + j * 16 + lr;
        float bv = bias[col];
        int cm = col & 1023;
        int h = cm >> 6, d = cm & 63;
#pragma unroll
        for (int r = 0; r < 4; r++) {
          float v = acc[i][j][r] + bv;
          int rt = row + r;
          int b = rt >> 11, t = rt & 2047;
          bf16 o = (bf16)v;
          size_t bh = (size_t)(b * H_ + h);
          if (sect == 0)      qb[(bh * T_ + t) * D_ + d] = o;   // [B,H,T,D]
          else if (sect == 1) kb[(bh * T_ + t) * D_ + d] = o;   // [B,H,T,D]
          else                vb[(bh * D_ + d) * T_ + t] = o;   // [B,H,D,T] (V^T)
        }
      }
    }
  }
}

// ---------------- flash attention (32x32 swapped-operand, in-register softmax) ----
// grid: (T/256, B*H); 256 threads = 4 waves, wave w owns 32 q rows.
// Work-balanced: block p handles qblk {NQ-1-p} then {p} -> 34 tiles/block flat.
// 3-buffer depth-2 prefetch, counted vmcnt(4) (T3/T4): load->wait gap = 2 tiles.

#if __has_builtin(__builtin_amdgcn_permlane32_swap)
#define PERMSWAP(A, B, LOW, HIW) do {                                           \
    auto _r = __builtin_amdgcn_permlane32_swap((unsigned)(A), (unsigned)(B),    \
                                               false, false);                   \
    __builtin_memcpy(&(LOW), &_r, 4);                                           \
    __builtin_memcpy(&(HIW), (const char*)&_r + 4, 4);                          \
  } while (0)
#else
#define PERMSWAP(A, B, LOW, HIW) do {                                           \
    unsigned _sb = (unsigned)__shfl_xor((int)(B), 32, 64);                      \
    unsigned _sa = (unsigned)__shfl_xor((int)(A), 32, 64);                      \
    (LOW) = hi ? _sb : (A);                                                     \
    (HIW) = hi ? (B) : _sa;                                                     \
  } while (0)
#endif

__global__ __launch_bounds__(256, 4)
void attn_fwd(const bf16* __restrict__ qg, const bf16* __restrict__ kg,
              const bf16* __restrict__ vg, bf16* __restrict__ yb) {
  __shared__ alignas(16) bf16 Ks[3][64 * 64];
  __shared__ alignas(16) bf16 Vs[3][64 * 64];   // V^T tile: [d][k_local]
  const int tid = threadIdx.x;
  const int lane = tid & 63, wid = tid >> 6;
  const int hi = lane >> 5, lq = lane & 31;
  const int xr = (lq & 7) << 4;
  const int bh = blockIdx.y;
  const int NQ = T_ / 128;

  const char* kbase = (const char*)(kg + (size_t)bh * T_ * D_);
  const char* vbase = (const char*)(vg + (size_t)bh * D_ * T_);
  const int b_ = bh >> 4, h = bh & 15;

#define STAGE(BF, TT) do {                                                     \
    _Pragma("unroll")                                                          \
    for (int j_ = 0; j_ < 2; ++j_) {                                           \
      int s_ = j_ * 256 + tid;                                                 \
      int row_ = s_ >> 3;                                                      \
      int scb_ = ((s_ & 7) << 4) ^ ((row_ & 7) << 4);                          \
      gld16(kbase + (size_t)((TT) * 64 + row_) * 128 + scb_,                   \
            (char*)Ks[BF] + s_ * 16);                                          \
      gld16(vbase + (size_t)row_ * (T_ * 2) + (TT) * 128 + scb_,               \
            (char*)Vs[BF] + s_ * 16);                                          \
    }                                                                          \
  } while (0)

  for (int ph = 0; ph < 2; ++ph) {
    const int qblk = ph ? (int)blockIdx.x : (NQ - 1 - (int)blockIdx.x);
    const int wq0 = qblk * 128 + wid * 32;
    const int qrow = wq0 + lq;
    const int nt = 2 * qblk + 2;

    if (ph) __builtin_amdgcn_s_barrier();   // all waves done reading LDS of ph0
    STAGE(0, 0);
    STAGE(1, 1);

    // Q B-fragments: lane holds q-col = qrow, d = 16s + 8hi + e
    const bf16* qptr = qg + ((size_t)bh * T_ + qrow) * D_ + hi * 8;
    bf16x8 qf[4];
#pragma unroll
    for (int s = 0; s < 4; s++) {
      qf[s] = *(const bf16x8*)(qptr + 16 * s);
      asm volatile("" : "+v"(qf[s]));
    }

    f32x16 o[2] = {};              // O^T: block db rows d=32db+crow, col q=lq
    float mrow = NEG_INF, lrow = 0.f;

    for (int t = 0; t < nt; ++t) {
      if (t + 1 < nt) asm volatile("s_waitcnt vmcnt(4)" ::: "memory");
      else            asm volatile("s_waitcnt vmcnt(0)" ::: "memory");
      __builtin_amdgcn_s_barrier();
      asm volatile("" ::: "memory");
      if (t + 2 < nt) STAGE((t + 2) % 3, t + 2);

      const char* Kc = (const char*)Ks[t % 3];
      const char* Vc = (const char*)Vs[t % 3];

      // S^T[k][q] for this wave's 32 q cols; 2 blocks of 32 k
      f32x16 S[2] = {};
      __builtin_amdgcn_s_setprio(1);
#pragma unroll
      for (int s = 0; s < 4; s++) {
#pragma unroll
        for (int b = 0; b < 2; b++) {
          bf16x8 kf = *(const bf16x8*)(Kc + (b * 32 + lq) * 128 +
                                       ((32 * s + 16 * hi) ^ xr));
          S[b] = __builtin_amdgcn_mfma_f32_32x32x16_bf16(kf, qf[s], S[b], 0, 0, 0);
        }
      }
      __builtin_amdgcn_s_setprio(0);

      // causal mask (raw-score domain)
      if (t >= nt - 2) {
#pragma unroll
        for (int b = 0; b < 2; b++)
#pragma unroll
          for (int r = 0; r < 16; r++) {
            int kgl = t * 64 + b * 32 + (r & 3) + 8 * (r >> 2) + 4 * hi;
            if (kgl > qrow) S[b][r] = NEG_INF;
          }
      }

      // online softmax, fully in-register (one cross-lane op per reduce)
      float tm = NEG_INF;
#pragma unroll
      for (int b = 0; b < 2; b++)
#pragma unroll
        for (int r = 0; r < 16; r++) tm = fmaxf(tm, S[b][r]);
      tm = fmaxf(tm, __shfl_xor(tm, 32, 64));

      float mn = fmaxf(mrow, 0.125f * tm);
      float alpha = __expf(mrow - mn);     // exp(-inf)=0 on first tile
      mrow = mn;
      float rs = 0.f;
#pragma unroll
      for (int b = 0; b < 2; b++)
#pragma unroll
        for (int r = 0; r < 16; r++) {
          float e = __expf(fmaf(S[b][r], 0.125f, -mn));
          S[b][r] = e;
          rs += e;
        }
      rs += __shfl_xor(rs, 32, 64);
      lrow = lrow * alpha + rs;
#pragma unroll
      for (int db = 0; db < 2; db++)
#pragma unroll
        for (int r = 0; r < 16; r++) o[db][r] *= alpha;

      // O^T += V^T * P^T ; P^T B-fragment built via cvt_pk + permlane32_swap
      __builtin_amdgcn_s_setprio(1);
#pragma unroll
      for (int ks = 0; ks < 4; ks++) {
        const int b = ks >> 1, hf = ks & 1;
        unsigned A0 = cvtpk(S[b][8 * hf + 0], S[b][8 * hf + 1]);
        unsigned A1 = cvtpk(S[b][8 * hf + 2], S[b][8 * hf + 3]);
        unsigned B0 = cvtpk(S[b][8 * hf + 4], S[b][8 * hf + 5]);
        unsigned B1 = cvtpk(S[b][8 * hf + 6], S[b][8 * hf + 7]);
        unsigned w0, w1, w2, w3;
        PERMSWAP(A0, B0, w0, w2);
        PERMSWAP(A1, B1, w1, w3);
        u32x4 wv = {w0, w1, w2, w3};
        bf16x8 pf = __builtin_bit_cast(bf16x8, wv);
#pragma unroll
        for (int db = 0; db < 2; db++) {
          bf16x8 vf = *(const bf16x8*)(Vc + (db * 32 + lq) * 128 +
                                       ((32 * ks + 16 * hi) ^ xr));
          o[db] = __builtin_amdgcn_mfma_f32_32x32x16_bf16(vf, pf, o[db], 0, 0, 0);
        }
      }
      __builtin_amdgcn_s_setprio(0);
    }

    // epilogue: O^T lane holds q=qrow col; d = 32db + 8rq + 4hi + rr
    float inv = 1.f / lrow;
    bf16* yrow = yb + ((size_t)(b_ * T_ + qrow)) * C_ + h * 64 + hi * 4;
#pragma unroll
    for (int db = 0; db < 2; db++)
#pragma unroll
      for (int rq = 0; rq < 4; rq++) {
        unsigned w0 = cvtpk(o[db][4 * rq + 0] * inv, o[db][4 * rq + 1] * inv);
        unsigned w1 = cvtpk(o[db][4 * rq + 2] * inv, o[db][4 * rq + 3] * inv);
        u32x2 wv = {w0, w1};
        *(u32x2*)(yrow + db * 32 + rq * 8) = wv;
      }
  }
#undef STAGE
}

// ---------------- launch ----------------

extern "C" void kernel_launch(void* const* d_in, const int* in_sizes, int n_in,
                              void* d_out, int out_size, void* d_ws, size_t ws_size,
                              hipStream_t stream) {
  (void)in_sizes; (void)n_in; (void)out_size; (void)ws_size;
  const float* x      = (const float*)d_in[0];
  const float* w_attn = (const float*)d_in[1];
  const float* b_attn = (const float*)d_in[2];
  const float* w_proj = (const float*)d_in[3];
  const float* b_proj = (const float*)d_in[4];
  float* out = (float*)d_out;

  char* ws = (char*)d_ws;
  bf16* x_bf = (bf16*)ws;  ws += (size_t)BT_ * C_ * 2;      // 16 MB
  bf16* wat  = (bf16*)ws;  ws += (size_t)3 * C_ * C_ * 2;   //  6 MB  [3C][C]
  bf16* wpt  = (bf16*)ws;  ws += (size_t)C_ * C_ * 2;       //  2 MB  [C][C]
  bf16* qbuf = (bf16*)ws;  ws += (size_t)BT_ * C_ * 2;      // 16 MB  [B,H,T,D]
  bf16* kbuf = (bf16*)ws;  ws += (size_t)BT_ * C_ * 2;      // 16 MB  [B,H,T,D]
  bf16* vbuf = (bf16*)ws;  ws += (size_t)BT_ * C_ * 2;      // 16 MB  [B,H,D,T]
  bf16* ybuf = (bf16*)ws;                                    // 16 MB  [B,T,C]

  cast_x<<<(BT_ * C_ / 4) / 256, 256, 0, stream>>>(x, x_bf);
  transpose_cast<<<dim3(3 * C_ / 32, C_ / 32), dim3(32, 8), 0, stream>>>(w_attn, wat, C_, 3 * C_);
  transpose_cast<<<dim3(C_ / 32, C_ / 32), dim3(32, 8), 0, stream>>>(w_proj, wpt, C_, C_);

  gemm_bt<0><<<dim3(3 * C_ / 128, BT_ / 128), 256, 0, stream>>>(
      x_bf, wat, b_attn, nullptr, qbuf, kbuf, vbuf, BT_, 3 * C_, C_);

  attn_fwd<<<dim3(T_ / 256, B_ * H_), 256, 0, stream>>>(qbuf, kbuf, vbuf, ybuf);

  gemm_bt<1><<<dim3(C_ / 128, BT_ / 128), 256, 0, stream>>>(
      ybuf, wpt, b_proj, out, nullptr, nullptr, nullptr, BT_, C_, C_);
}